// Round 10
// baseline (227.217 us; speedup 1.0000x reference)
//
#include <hip/hip_runtime.h>
#include <stdint.h>

typedef __attribute__((ext_vector_type(8))) short short8;
typedef __attribute__((ext_vector_type(4))) short short4v;
typedef __attribute__((ext_vector_type(4))) float float4v;

#define MFMA16(a, b, c) __builtin_amdgcn_mfma_f32_16x16x32_bf16((a), (b), (c), 0, 0, 0)

__device__ __forceinline__ ushort f2bf_rne(float f) {
  union { float f; unsigned u; } x; x.f = f;
  unsigned r = x.u + 0x7FFFu + ((x.u >> 16) & 1u);
  return (ushort)(r >> 16);
}
__device__ __forceinline__ ushort f2bf_trunc(float f) {
  union { float f; unsigned u; } x; x.f = f;
  return (ushort)(x.u >> 16);
}
__device__ __forceinline__ void gload16(const ushort* g, ushort* lds) {
  __builtin_amdgcn_global_load_lds(
      (__attribute__((address_space(1))) unsigned int*)g,
      (__attribute__((address_space(3))) unsigned int*)lds, 16, 0, 0);
}

// scale*log2(e): baked into Qh so attention uses raw exp2 on scores.
#define CEXP 0.1803368801111204f

// ---------------------------------------------------------------------------
// 64x64 transpose (f32 in, bf16 out): out[c*os + r] = bf16(in[r*is + c])
// ---------------------------------------------------------------------------
__device__ __forceinline__ void transpose64f(const float* __restrict__ in, int is,
                                             ushort* __restrict__ out, int os,
                                             ushort* lds /*64*72*/) {
  const int t = threadIdx.x;
#pragma unroll
  for (int it = 0; it < 2; ++it) {
    int e = it * 2048 + t * 8;
    int r = e >> 6, c = e & 63;
    const float* p = in + (size_t)r * is + c;
    float4 x0 = *(const float4*)p;
    float4 x1 = *(const float4*)(p + 4);
    ushort tv[8] __attribute__((aligned(16))) = {
        f2bf_rne(x0.x), f2bf_rne(x0.y), f2bf_rne(x0.z), f2bf_rne(x0.w),
        f2bf_rne(x1.x), f2bf_rne(x1.y), f2bf_rne(x1.z), f2bf_rne(x1.w)};
    *(uint4*)&lds[r * 72 + c] = *(const uint4*)tv;
  }
  __syncthreads();
  const int cc = t >> 2;
  const int rg = (t & 3) * 16;
  ushort tmp[16] __attribute__((aligned(16)));
#pragma unroll
  for (int i = 0; i < 16; ++i) tmp[i] = lds[(rg + i) * 72 + cc];
  *(uint4*)&out[(size_t)cc * os + rg] = *(const uint4*)&tmp[0];
  *(uint4*)&out[(size_t)cc * os + rg + 8] = *(const uint4*)&tmp[8];
}

// ---------------------------------------------------------------------------
// prep (R10): Wo f32->bf16 convert (512 blocks) + Wq/Wk/Wv repack (768).
// QKV conversion DELETED -- proj3 now stages f32 directly with inline
// f2bf_rne (identical numerics, one fewer full pass over 72 MB).
// grid.x = 1280.
// ---------------------------------------------------------------------------
__global__ __launch_bounds__(256) void prep_kernel(
    const float* __restrict__ Wo, const float* __restrict__ Wq,
    const float* __restrict__ Wk, const float* __restrict__ Wv,
    ushort* __restrict__ WoB, ushort* __restrict__ BtQ, ushort* __restrict__ BtK,
    ushort* __restrict__ BtV) {
  __shared__ ushort lds[64 * 72];
  const int bx = blockIdx.x;
  if (bx < 512) {
    const int i = (bx * 256 + threadIdx.x) * 8;
    float4 a = *(const float4*)(Wo + i);
    float4 b = *(const float4*)(Wo + i + 4);
    ushort t[8] __attribute__((aligned(16))) = {
        f2bf_rne(a.x), f2bf_rne(a.y), f2bf_rne(a.z), f2bf_rne(a.w),
        f2bf_rne(b.x), f2bf_rne(b.y), f2bf_rne(b.z), f2bf_rne(b.w)};
    *(uint4*)(WoB + i) = *(const uint4*)t;
  } else {
    const int rb = bx - 512;
    const int dt = rb & 15, h = (rb >> 4) & 15, z = rb >> 8;
    const float* W = z == 0 ? Wq : (z == 1 ? Wk : Wv);
    ushort* Bt = z == 0 ? BtQ : (z == 1 ? BtK : BtV);
    transpose64f(W + h * 65536 + dt * 4096, 64, Bt + h * 65536 + dt * 64, 1024, lds);
  }
}

// standalone repack for the fallback path
__global__ __launch_bounds__(256, 2) void repack_w_kernel(
    const float* __restrict__ Wq, const float* __restrict__ Wk,
    const float* __restrict__ Wv, ushort* __restrict__ BtQ, ushort* __restrict__ BtK,
    ushort* __restrict__ BtV) {
  __shared__ ushort lds[64 * 72];
  const float* W = blockIdx.z == 0 ? Wq : (blockIdx.z == 1 ? Wk : Wv);
  ushort* Bt = blockIdx.z == 0 ? BtQ : (blockIdx.z == 1 ? BtK : BtV);
  const int h = blockIdx.y, dt = blockIdx.x;
  transpose64f(W + h * 65536 + dt * 4096, 64, Bt + h * 65536 + dt * 64, 1024, lds);
}

// ---------------------------------------------------------------------------
// Double-buffered 1-barrier GEMM: C = (A[M,K] @ Bt[N,K]^T + bias)*ascale.
// LDS chunk swizzle: slot (row, chunk) holds global chunk (chunk ^ (row&3));
// linear dest + swizzled global source + swizzled read (rule #21).
// mbase/nbase are parameters (XCD panel-grouping remap done by caller).
// cmode: 0 bf16 row-major, 1 bf16 scatter Vt (fallback only), 2 f32 row-major,
//        3 bf16 coalesced-transpose into Vt[b,h,dk,t] (lA scratch >= 9216 B).
// ---------------------------------------------------------------------------
template <int F32>
__device__ __forceinline__ void stage16(const void* G, size_t eoff, ushort* ldst) {
  if (F32) {
    const float* p = (const float*)G + eoff;
    float4 x0 = *(const float4*)p;
    float4 x1 = *(const float4*)(p + 4);
    ushort t[8] __attribute__((aligned(16))) = {
        f2bf_rne(x0.x), f2bf_rne(x0.y), f2bf_rne(x0.z), f2bf_rne(x0.w),
        f2bf_rne(x1.x), f2bf_rne(x1.y), f2bf_rne(x1.z), f2bf_rne(x1.w)};
    *(uint4*)ldst = *(const uint4*)t;
  } else {
    gload16((const ushort*)G + eoff, ldst);
  }
}

template <int AF32, int BF32>
__device__ __forceinline__ void gemm_body_basic(const void* __restrict__ A,
                                                const void* __restrict__ Bt,
                                                const float* __restrict__ bias,
                                                void* __restrict__ C, int cmode,
                                                float ascale, int N, int K, int mbase,
                                                int nbase, ushort* lA, ushort* lB) {
  const int tid = threadIdx.x;
  const int l = tid & 63, lane15 = l & 15, quad = l >> 4;
  const int w = tid >> 6;
  const int wrow = (w >> 1) * 64, wcol = (w & 1) * 64;
  const int e0 = tid * 8;
  const int e1 = 2048 + tid * 8;
  const int r0 = tid >> 2;        // rows 0..63 (e0); e1 rows r0+64
  const int r1 = r0 + 64;
  const int cs = ((tid & 3) ^ (r0 & 3)) * 8;
  const int rsw = lane15 & 3;     // read-side row-swizzle bits

  float4v acc[4][4];
#pragma unroll
  for (int i = 0; i < 4; ++i)
#pragma unroll
    for (int j = 0; j < 4; ++j) acc[i][j] = (float4v){0.f, 0.f, 0.f, 0.f};

  // prologue: stage kb=0 into buffer 0
  stage16<AF32>(A, (size_t)(mbase + r0) * K + cs, &lA[e0]);
  stage16<AF32>(A, (size_t)(mbase + r1) * K + cs, &lA[e1]);
  stage16<BF32>(Bt, (size_t)(nbase + r0) * K + cs, &lB[e0]);
  stage16<BF32>(Bt, (size_t)(nbase + r1) * K + cs, &lB[e1]);
  asm volatile("s_waitcnt vmcnt(0)" ::: "memory");
  __syncthreads();

  int cur = 0;
  for (int kb = 0; kb < K; kb += 32) {
    const int nxt = cur ^ 1;
    if (kb + 32 < K) {
      stage16<AF32>(A, (size_t)(mbase + r0) * K + cs + kb + 32, &lA[nxt * 4096 + e0]);
      stage16<AF32>(A, (size_t)(mbase + r1) * K + cs + kb + 32, &lA[nxt * 4096 + e1]);
      stage16<BF32>(Bt, (size_t)(nbase + r0) * K + cs + kb + 32, &lB[nxt * 4096 + e0]);
      stage16<BF32>(Bt, (size_t)(nbase + r1) * K + cs + kb + 32, &lB[nxt * 4096 + e1]);
    }
    const ushort* cA = &lA[cur * 4096];
    const ushort* cB = &lB[cur * 4096];
    short8 a[4], b[4];
#pragma unroll
    for (int i = 0; i < 4; ++i) {
      a[i] = *(const short8*)&cA[(wrow + i * 16 + lane15) * 32 + (quad ^ rsw) * 8];
      b[i] = *(const short8*)&cB[(wcol + i * 16 + lane15) * 32 + (quad ^ rsw) * 8];
    }
#pragma unroll
    for (int i = 0; i < 4; ++i)
#pragma unroll
      for (int j = 0; j < 4; ++j) acc[i][j] = MFMA16(a[i], b[j], acc[i][j]);
    asm volatile("s_waitcnt vmcnt(0)" ::: "memory");
    __syncthreads();
    cur = nxt;
  }

  if (cmode == 3) {
    // coalesced transposed epilogue into Vt[b,h,dk,t] via per-wave LDS scratch
    __syncthreads();
    uint* sp = (uint*)lA + w * 576;  // 2304 B/wave, lA is 16 KB
    const int bb = mbase >> 11;
    const int tb = (mbase & 2047) + wrow;
#pragma unroll
    for (int j = 0; j < 4; ++j) {
      {
        const int n = nbase + wcol + j * 16 + lane15;
        const float bvs = bias[n];
#pragma unroll
        for (int i = 0; i < 4; ++i)
#pragma unroll
          for (int rp = 0; rp < 2; ++rp) {
            const uint lo = f2bf_rne((acc[i][j][2 * rp] + bvs) * ascale);
            const uint hi = f2bf_rne((acc[i][j][2 * rp + 1] + bvs) * ascale);
            sp[36 * lane15 + i * 8 + quad * 2 + rp] = lo | (hi << 16);
          }
      }
#pragma unroll
      for (int t = 0; t < 2; ++t) {
        const int row = t * 8 + (l >> 3);
        const int c = l & 7;
        uint4 d = *(const uint4*)(sp + 36 * row + 4 * c);
        const int ng = nbase + wcol + j * 16 + row;
        ushort* dst = (ushort*)C + ((size_t)(bb * 1024 + ng)) * 2048 + tb + c * 8;
        *(uint4*)dst = d;
      }
    }
    return;
  }

#pragma unroll
  for (int j = 0; j < 4; ++j) {
    const int n = nbase + wcol + j * 16 + lane15;
    const float bvs = bias[n];
#pragma unroll
    for (int i = 0; i < 4; ++i) {
      const int m0 = mbase + wrow + i * 16 + quad * 4;
#pragma unroll
      for (int r = 0; r < 4; ++r) {
        const float val = (acc[i][j][r] + bvs) * ascale;
        if (cmode == 1) {
          const int m = m0 + r;
          const int bb = m >> 11, t = m & 2047;
          ((ushort*)C)[((size_t)(bb * 1024 + n)) * 2048 + t] = f2bf_rne(val);
        } else if (cmode == 2) {
          ((float*)C)[(size_t)(m0 + r) * N + n] = val;
        } else {
          ((ushort*)C)[(size_t)(m0 + r) * N + n] = f2bf_rne(val);
        }
      }
    }
  }
}

// main-path projections (R10: f32 A operands staged with inline f2bf_rne;
// deletes the prep QKV pass). 1-D grid 768 with XCD panel-grouping.
__global__ __launch_bounds__(256, 2) void proj3_kernel(
    const float* __restrict__ Q, const float* __restrict__ K,
    const float* __restrict__ V, const ushort* __restrict__ BtQ,
    const ushort* __restrict__ BtK, const ushort* __restrict__ BtV,
    const float* __restrict__ bq, const float* __restrict__ bk,
    const float* __restrict__ bv, ushort* __restrict__ Qh, ushort* __restrict__ Kh,
    ushort* __restrict__ Vt) {
  __shared__ ushort lA[8192], lB[8192];
  const int lin = blockIdx.x;
  const int xcd = lin & 7;
  const int slot = lin >> 3;
  const int panel = xcd * 12 + (slot >> 3);  // 0..95
  const int nb = slot & 7;
  const int zz = panel >> 5;       // 0..2
  const int yb = panel & 31;       // 0..31
  const int mbase = yb * 128, nbase = nb * 128;
  if (zz == 0)
    gemm_body_basic<1, 0>(Q, BtQ, bq, Qh, 0, CEXP, 1024, 1024, mbase, nbase, lA, lB);
  else if (zz == 1)
    gemm_body_basic<1, 0>(K, BtK, bk, Kh, 0, 1.0f, 1024, 1024, mbase, nbase, lA, lB);
  else
    gemm_body_basic<1, 0>(V, BtV, bv, Vt, 3, 1.0f, 1024, 1024, mbase, nbase, lA, lB);
}

// ---------------------------------------------------------------------------
// Output projection: 128(M)x64(N) tiles, 1-D grid 512 with XCD grouping.
// Double-buffered (24 KB LDS), one barrier per K-step, chunk-swizzled LDS.
// ---------------------------------------------------------------------------
__global__ __launch_bounds__(256, 2) void gemm_out_kernel(
    const ushort* __restrict__ X, const ushort* __restrict__ WoB,
    const float* __restrict__ bo, float* __restrict__ out) {
  __shared__ ushort lA[8192], lB[4096];
  const int lin = blockIdx.x;
  const int xcd = lin & 7;
  const int slot = lin >> 3;        // 0..63
  const int panel = xcd * 4 + (slot >> 4);  // 0..31
  const int nb = slot & 15;
  const int mbase = panel * 128, nbase = nb * 64;
  const int tid = threadIdx.x;
  const int l = tid & 63, lane15 = l & 15, quad = l >> 4;
  const int wv = tid >> 6;
  const int wrow = wv * 32;
  const int e0 = tid * 8;
  const int e1 = 2048 + tid * 8;
  const int r0 = tid >> 2;
  const int r1 = r0 + 64;
  const int cs = ((tid & 3) ^ (r0 & 3)) * 8;
  const int rsw = lane15 & 3;
  const ushort* Ag0 = X + (size_t)(mbase + r0) * 1024 + cs;
  const ushort* Ag1 = X + (size_t)(mbase + r1) * 1024 + cs;
  const ushort* Bg0 = WoB + (size_t)(nbase + r0) * 1024 + cs;

  float4v acc[2][4];
#pragma unroll
  for (int i = 0; i < 2; ++i)
#pragma unroll
    for (int j = 0; j < 4; ++j) acc[i][j] = (float4v){0.f, 0.f, 0.f, 0.f};

  // prologue: stage kb=0 into buffer 0
  gload16(Ag0, &lA[e0]);
  gload16(Ag1, &lA[e1]);
  gload16(Bg0, &lB[e0]);
  asm volatile("s_waitcnt vmcnt(0)" ::: "memory");
  __syncthreads();

  int cur = 0;
  for (int kb = 0; kb < 1024; kb += 32) {
    const int nxt = cur ^ 1;
    if (kb + 32 < 1024) {
      gload16(Ag0 + kb + 32, &lA[nxt * 4096 + e0]);
      gload16(Ag1 + kb + 32, &lA[nxt * 4096 + e1]);
      gload16(Bg0 + kb + 32, &lB[nxt * 2048 + e0]);
    }
    const ushort* cA = &lA[cur * 4096];
    const ushort* cB = &lB[cur * 2048];
    short8 a[2], b[4];
#pragma unroll
    for (int i = 0; i < 2; ++i)
      a[i] = *(const short8*)&cA[(wrow + i * 16 + lane15) * 32 + (quad ^ rsw) * 8];
#pragma unroll
    for (int j = 0; j < 4; ++j)
      b[j] = *(const short8*)&cB[(j * 16 + lane15) * 32 + (quad ^ rsw) * 8];
#pragma unroll
    for (int i = 0; i < 2; ++i)
#pragma unroll
      for (int j = 0; j < 4; ++j) acc[i][j] = MFMA16(a[i], b[j], acc[i][j]);
    asm volatile("s_waitcnt vmcnt(0)" ::: "memory");
    __syncthreads();
    cur = nxt;
  }

#pragma unroll
  for (int j = 0; j < 4; ++j) {
    const int n = nbase + j * 16 + lane15;
    const float bvs = bo[n];
#pragma unroll
    for (int i = 0; i < 2; ++i) {
      const int m0 = mbase + wrow + i * 16 + quad * 4;
#pragma unroll
      for (int r = 0; r < 4; ++r) out[(size_t)(m0 + r) * 1024 + n] = acc[i][j][r] + bvs;
    }
  }
}

// fallback-path kernels (f32 operands)
__global__ __launch_bounds__(256, 2) void proj3f_kernel(
    const float* __restrict__ Q, const float* __restrict__ Kin,
    const float* __restrict__ V, const ushort* __restrict__ BtQ,
    const ushort* __restrict__ BtK, const ushort* __restrict__ BtV,
    const float* __restrict__ bq, const float* __restrict__ bk,
    const float* __restrict__ bv, ushort* __restrict__ Qh, ushort* __restrict__ Kh,
    ushort* __restrict__ Vt) {
  __shared__ ushort lA[8192], lB[8192];
  const int mbase = blockIdx.y * 128, nbase = blockIdx.x * 128;
  if (blockIdx.z == 0)
    gemm_body_basic<1, 0>(Q, BtQ, bq, Qh, 0, CEXP, 1024, 1024, mbase, nbase, lA, lB);
  else if (blockIdx.z == 1)
    gemm_body_basic<1, 0>(Kin, BtK, bk, Kh, 0, 1.0f, 1024, 1024, mbase, nbase, lA, lB);
  else
    gemm_body_basic<1, 0>(V, BtV, bv, Vt, 3, 1.0f, 1024, 1024, mbase, nbase, lA, lB);
}

__global__ __launch_bounds__(256, 2) void gemm_btf_kernel(
    const ushort* __restrict__ X, const float* __restrict__ Wo,
    const float* __restrict__ bo, float* __restrict__ out) {
  __shared__ ushort lA[8192], lB[8192];
  const int mbase = blockIdx.y * 128, nbase = blockIdx.x * 128;
  gemm_body_basic<0, 1>(X, Wo, bo, out, 2, 1.0f, 1024, 1024, mbase, nbase, lA, lB);
}

// ---------------------------------------------------------------------------
// Flash attention v11 (verified 43.7 us): pipe-interleaved tile body on v6's
// verified sync structure. QK-all -> sm-half1 -> V-reads -> PV-half1 ->
// sm-half2 -> PV-half2; one vmcnt(0)+barrier per tile. UNTOUCHED this round.
// ---------------------------------------------------------------------------
__global__ __launch_bounds__(512, 4) void attn_kernel(const ushort* __restrict__ Qh,
                                                      const ushort* __restrict__ Kh,
                                                      const ushort* __restrict__ Vt,
                                                      ushort* __restrict__ ctxout) {
  __shared__ ushort lK[2][64 * 64];
  __shared__ ushort lV[2][64 * 64];
  const int tid = threadIdx.x, l = tid & 63, wv = tid >> 6;
  const int lane15 = l & 15, quad = l >> 4;
  const int bh = blockIdx.x, b = bh >> 4, h = bh & 15;
  const int q0 = blockIdx.y * 128 + wv * 16;

  const int sr = tid >> 3;
  const int scb = (tid & 7) ^ (sr & 7);
  const ushort* Kp = Kh + (size_t)(b * 2048) * 1024 + h * 64;
  const ushort* Vp = Vt + (size_t)(bh * 64) * 2048;
  const ushort* Kg = Kp + (size_t)sr * 1024 + scb * 8;
  const ushort* Vg = Vp + (size_t)sr * 2048 + scb * 8;

  const ushort* qrow = Qh + (size_t)(b * 2048 + q0 + lane15) * 1024 + h * 64;
  const short8 qa0 = *(const short8*)&qrow[quad * 8];
  const short8 qa1 = *(const short8*)&qrow[32 + quad * 8];

  const int xm = lane15 & 7;
  const int fr0 = lane15 * 64 + ((quad ^ xm) * 8);
  const int fr1 = lane15 * 64 + (((quad + 4) ^ xm) * 8);

  const short8 ones = {0x3F80, 0x3F80, 0x3F80, 0x3F80, 0x3F80, 0x3F80, 0x3F80, 0x3F80};

  float4v o[4];
  float4v lf = (float4v){0.f, 0.f, 0.f, 0.f};
#pragma unroll
  for (int i = 0; i < 4; ++i) o[i] = (float4v){0.f, 0.f, 0.f, 0.f};

  gload16(Kg, &lK[0][tid * 8]);
  gload16(Vg, &lV[0][tid * 8]);
  asm volatile("s_waitcnt vmcnt(0)" ::: "memory");
  __syncthreads();

  union PK { uint w[4]; short8 v; };

  int cur = 0;
  for (int s0 = 0; s0 < 2048; s0 += 64) {
    if (s0 + 64 < 2048) {
      gload16(Kg + (size_t)(s0 + 64) * 1024, &lK[cur ^ 1][tid * 8]);
      gload16(Vg + (s0 + 64), &lV[cur ^ 1][tid * 8]);
    }
    const ushort* Kl = &lK[cur][0];
    const ushort* Vl = &lV[cur][0];

    // --- QK for all 4 s-16-blocks (8 MFMAs fill the matrix pipe) ---
    float4v sb[4];
    __builtin_amdgcn_s_setprio(1);
#pragma unroll
    for (int i = 0; i < 4; ++i) {
      short8 k0 = *(const short8*)&Kl[i * 1024 + fr0];
      short8 k1 = *(const short8*)&Kl[i * 1024 + fr1];
      float4v c = (float4v){0.f, 0.f, 0.f, 0.f};
      c = MFMA16(k0, qa0, c);
      c = MFMA16(k1, qa1, c);
      sb[i] = c;
    }
    __builtin_amdgcn_s_setprio(0);

    // --- softmax half 1 (i=0,1) -> pa0, under the QK pipe drain ---
    uint wpk[4][2];
#pragma unroll
    for (int i = 0; i < 2; ++i) {
      const float e0 = __builtin_amdgcn_exp2f(sb[i][0]);
      const float e1 = __builtin_amdgcn_exp2f(sb[i][1]);
      const float e2 = __builtin_amdgcn_exp2f(sb[i][2]);
      const float e3 = __builtin_amdgcn_exp2f(sb[i][3]);
      asm("v_cvt_pk_bf16_f32 %0, %1, %2" : "=v"(wpk[i][0]) : "v"(e0), "v"(e1));
      asm("v_cvt_pk_bf16_f32 %0, %1, %2" : "=v"(wpk[i][1]) : "v"(e2), "v"(e3));
    }
    PK u0;
    {
      uint a0 = wpk[0][0], b0 = wpk[1][0];
      asm("v_permlane32_swap_b32 %0, %1" : "+v"(a0), "+v"(b0));
      asm("v_permlane16_swap_b32 %0, %1" : "+v"(a0), "+v"(b0));
      uint a1 = wpk[0][1], b1 = wpk[1][1];
      asm("v_permlane32_swap_b32 %0, %1" : "+v"(a1), "+v"(b1));
      asm("v_permlane16_swap_b32 %0, %1" : "+v"(a1), "+v"(b1));
      u0.w[0] = a0; u0.w[1] = a1; u0.w[2] = b0; u0.w[3] = b1;
    }
    const short8 pa0 = u0.v;

    // --- V fragment reads (ds pipe runs under MFMA issue) ---
    short8 vv0[4], vv1[4];
#pragma unroll
    for (int nf = 0; nf < 4; ++nf) {
      vv0[nf] = *(const short8*)&Vl[nf * 1024 + fr0];
      vv1[nf] = *(const short8*)&Vl[nf * 1024 + fr1];
    }

    // --- PV half 1 (pa0) fills the matrix pipe... ---
    __builtin_amdgcn_s_setprio(1);
    lf = MFMA16(pa0, ones, lf);
#pragma unroll
    for (int nf = 0; nf < 4; ++nf) o[nf] = MFMA16(pa0, vv0[nf], o[nf]);
    __builtin_amdgcn_s_setprio(0);

    // --- ...while softmax half 2 (i=2,3) -> pa1 runs on VALU/trans ---
#pragma unroll
    for (int i = 2; i < 4; ++i) {
      const float e0 = __builtin_amdgcn_exp2f(sb[i][0]);
      const float e1 = __builtin_amdgcn_exp2f(sb[i][1]);
      const float e2 = __builtin_amdgcn_exp2f(sb[i][2]);
      const float e3 = __builtin_amdgcn_exp2f(sb[i][3]);
      asm("v_cvt_pk_bf16_f32 %0, %1, %2" : "=v"(wpk[i][0]) : "v"(e0), "v"(e1));
      asm("v_cvt_pk_bf16_f32 %0, %1, %2" : "=v"(wpk[i][1]) : "v"(e2), "v"(e3));
    }
    PK u1;
    {
      uint a2 = wpk[2][0], b2 = wpk[3][0];
      asm("v_permlane32_swap_b32 %0, %1" : "+v"(a2), "+v"(b2));
      asm("v_permlane16_swap_b32 %0, %1" : "+v"(a2), "+v"(b2));
      uint a3 = wpk[2][1], b3 = wpk[3][1];
      asm("v_permlane32_swap_b32 %0, %1" : "+v"(a3), "+v"(b3));
      asm("v_permlane16_swap_b32 %0, %1" : "+v"(a3), "+v"(b3));
      u1.w[0] = a2; u1.w[1] = a3; u1.w[2] = b2; u1.w[3] = b3;
    }
    const short8 pa1 = u1.v;

    // --- PV half 2 (pa1) ---
    __builtin_amdgcn_s_setprio(1);
    lf = MFMA16(pa1, ones, lf);
#pragma unroll
    for (int nf = 0; nf < 4; ++nf) o[nf] = MFMA16(pa1, vv1[nf], o[nf]);
    __builtin_amdgcn_s_setprio(0);

    asm volatile("s_waitcnt vmcnt(0)" ::: "memory");
    __syncthreads();
    cur ^= 1;
  }

  float inv[4];
#pragma unroll
  for (int r = 0; r < 4; ++r) inv[r] = (lf[r] > 0.f) ? 1.0f / lf[r] : 0.0f;
  ushort* crow = ctxout + ((size_t)bh * 2048 + q0) * 64;
#pragma unroll
  for (int nf = 0; nf < 4; ++nf)
#pragma unroll
    for (int r = 0; r < 4; ++r)
      crow[(size_t)(quad * 4 + r) * 64 + nf * 16 + lane15] = f2bf_rne(o[nf][r] * inv[r]);
}

// ---------------------------------------------------------------------------
extern "C" void kernel_launch(void* const* d_in, const int* in_sizes, int n_in,
                              void* d_out, int out_size, void* d_ws, size_t ws_size,
                              hipStream_t stream) {
  const float* Q = (const float*)d_in[0];
  const float* K = (const float*)d_in[1];
  const float* V = (const float*)d_in[2];
  const float* Wq = (const float*)d_in[3];
  const float* bq = (const float*)d_in[4];
  const float* Wk = (const float*)d_in[5];
  const float* bk = (const float*)d_in[6];
  const float* Wv = (const float*)d_in[7];
  const float* bv = (const float*)d_in[8];
  const float* Wo = (const float*)d_in[9];
  const float* bo = (const float*)d_in[10];
  float* out = (float*)d_out;
  ushort* ws = (ushort*)d_ws;

  if (ws_size >= (58ull << 20)) {
    // big path (u16 units):
    // [Qh 4M][Kh 4M][Vt 4M][Bt 3M (X 4M aliases)][WoB 1M @16M]
    // (Qb/Kb/Vb slots unused since R10 -- proj3 stages f32 directly)
    ushort* Qh = ws;
    ushort* Kh = Qh + (4 << 20);
    ushort* Vt = Kh + (4 << 20);
    ushort* BtQ = Vt + (4 << 20);
    ushort* BtK = BtQ + (1 << 20);
    ushort* BtV = BtK + (1 << 20);
    ushort* X = BtQ;  // 4M; Bt dead after proj3
    ushort* WoB = ws + (16ull << 20);

    prep_kernel<<<dim3(1280), 256, 0, stream>>>(Wo, Wq, Wk, Wv, WoB, BtQ, BtK, BtV);
    proj3_kernel<<<dim3(768), 256, 0, stream>>>(Q, K, V, BtQ, BtK, BtV, bq, bk, bv,
                                                Qh, Kh, Vt);
    attn_kernel<<<dim3(32, 16), 512, 0, stream>>>(Qh, Kh, Vt, X);
    gemm_out_kernel<<<dim3(512), 256, 0, stream>>>(X, WoB, bo, out);
  } else {
    // fallback (32 MB): f32 A/B staging in the GEMMs
    ushort* Qh = ws;
    ushort* Kh = Qh + (4 << 20);
    ushort* Vt = Kh + (4 << 20);
    ushort* R = Vt + (4 << 20);
    ushort* BtQ = R;
    ushort* BtK = R + (1 << 20);
    ushort* BtV = R + (2 << 20);
    ushort* X = R;

    repack_w_kernel<<<dim3(16, 16, 3), 256, 0, stream>>>(Wq, Wk, Wv, BtQ, BtK, BtV);
    proj3f_kernel<<<dim3(8, 32, 3), 256, 0, stream>>>(Q, K, V, BtQ, BtK, BtV, bq, bk, bv,
                                                      Qh, Kh, Vt);
    attn_kernel<<<dim3(32, 16), 512, 0, stream>>>(Qh, Kh, Vt, X);
    gemm_btf_kernel<<<dim3(8, 32), 256, 0, stream>>>(X, Wo, bo, out);
  }
}

// Round 11
// 213.572 us; speedup vs baseline: 1.0639x; 1.0639x over previous
//
#include <hip/hip_runtime.h>
#include <stdint.h>

typedef __attribute__((ext_vector_type(8))) short short8;
typedef __attribute__((ext_vector_type(4))) short short4v;
typedef __attribute__((ext_vector_type(4))) float float4v;

#define MFMA16(a, b, c) __builtin_amdgcn_mfma_f32_16x16x32_bf16((a), (b), (c), 0, 0, 0)

__device__ __forceinline__ ushort f2bf_rne(float f) {
  union { float f; unsigned u; } x; x.f = f;
  unsigned r = x.u + 0x7FFFu + ((x.u >> 16) & 1u);
  return (ushort)(r >> 16);
}
__device__ __forceinline__ ushort f2bf_trunc(float f) {
  union { float f; unsigned u; } x; x.f = f;
  return (ushort)(x.u >> 16);
}
__device__ __forceinline__ void gload16(const ushort* g, ushort* lds) {
  __builtin_amdgcn_global_load_lds(
      (__attribute__((address_space(1))) unsigned int*)g,
      (__attribute__((address_space(3))) unsigned int*)lds, 16, 0, 0);
}

// scale*log2(e): baked into Qh so attention uses raw exp2 on scores.
#define CEXP 0.1803368801111204f

// ---------------------------------------------------------------------------
// 64x64 transpose (f32 in, bf16 out): out[c*os + r] = bf16(in[r*is + c])
// ---------------------------------------------------------------------------
__device__ __forceinline__ void transpose64f(const float* __restrict__ in, int is,
                                             ushort* __restrict__ out, int os,
                                             ushort* lds /*64*72*/) {
  const int t = threadIdx.x;
#pragma unroll
  for (int it = 0; it < 2; ++it) {
    int e = it * 2048 + t * 8;
    int r = e >> 6, c = e & 63;
    const float* p = in + (size_t)r * is + c;
    float4 x0 = *(const float4*)p;
    float4 x1 = *(const float4*)(p + 4);
    ushort tv[8] __attribute__((aligned(16))) = {
        f2bf_rne(x0.x), f2bf_rne(x0.y), f2bf_rne(x0.z), f2bf_rne(x0.w),
        f2bf_rne(x1.x), f2bf_rne(x1.y), f2bf_rne(x1.z), f2bf_rne(x1.w)};
    *(uint4*)&lds[r * 72 + c] = *(const uint4*)tv;
  }
  __syncthreads();
  const int cc = t >> 2;
  const int rg = (t & 3) * 16;
  ushort tmp[16] __attribute__((aligned(16)));
#pragma unroll
  for (int i = 0; i < 16; ++i) tmp[i] = lds[(rg + i) * 72 + cc];
  *(uint4*)&out[(size_t)cc * os + rg] = *(const uint4*)&tmp[0];
  *(uint4*)&out[(size_t)cc * os + rg + 8] = *(const uint4*)&tmp[8];
}

// ---------------------------------------------------------------------------
// prep: f32->bf16 convert of Q,K,V (4M each) + Wo (1M), and Wq/Wk/Wv repack.
// grid.x = 6144 (QKV) + 512 (Wo) + 768 (repack) = 7424
// (R10's reg-staged f32 proj3 regressed 42->75 us -- m151: gload_lds beats
// reg-staging; the prep convert pass is net cheaper. Restored.)
// ---------------------------------------------------------------------------
__global__ __launch_bounds__(256) void prep_kernel(
    const float* __restrict__ Q, const float* __restrict__ K,
    const float* __restrict__ V, const float* __restrict__ Wo,
    const float* __restrict__ Wq, const float* __restrict__ Wk,
    const float* __restrict__ Wv, ushort* __restrict__ Qb, ushort* __restrict__ Kb,
    ushort* __restrict__ Vb, ushort* __restrict__ WoB, ushort* __restrict__ BtQ,
    ushort* __restrict__ BtK, ushort* __restrict__ BtV) {
  __shared__ ushort lds[64 * 72];
  const int bx = blockIdx.x;
  if (bx < 6656) {
    const float* s;
    ushort* d;
    int i;
    if (bx < 6144) {
      const int plane = bx >> 11;
      s = plane == 0 ? Q : (plane == 1 ? K : V);
      d = plane == 0 ? Qb : (plane == 1 ? Kb : Vb);
      i = ((bx & 2047) * 256 + threadIdx.x) * 8;
    } else {
      s = Wo;
      d = WoB;
      i = ((bx - 6144) * 256 + threadIdx.x) * 8;
    }
    float4 a = *(const float4*)(s + i);
    float4 b = *(const float4*)(s + i + 4);
    ushort t[8] __attribute__((aligned(16))) = {
        f2bf_rne(a.x), f2bf_rne(a.y), f2bf_rne(a.z), f2bf_rne(a.w),
        f2bf_rne(b.x), f2bf_rne(b.y), f2bf_rne(b.z), f2bf_rne(b.w)};
    *(uint4*)(d + i) = *(const uint4*)t;
  } else {
    const int rb = bx - 6656;
    const int dt = rb & 15, h = (rb >> 4) & 15, z = rb >> 8;
    const float* W = z == 0 ? Wq : (z == 1 ? Wk : Wv);
    ushort* Bt = z == 0 ? BtQ : (z == 1 ? BtK : BtV);
    transpose64f(W + h * 65536 + dt * 4096, 64, Bt + h * 65536 + dt * 64, 1024, lds);
  }
}

// standalone repack for the fallback path
__global__ __launch_bounds__(256, 2) void repack_w_kernel(
    const float* __restrict__ Wq, const float* __restrict__ Wk,
    const float* __restrict__ Wv, ushort* __restrict__ BtQ, ushort* __restrict__ BtK,
    ushort* __restrict__ BtV) {
  __shared__ ushort lds[64 * 72];
  const float* W = blockIdx.z == 0 ? Wq : (blockIdx.z == 1 ? Wk : Wv);
  ushort* Bt = blockIdx.z == 0 ? BtQ : (blockIdx.z == 1 ? BtK : BtV);
  const int h = blockIdx.y, dt = blockIdx.x;
  transpose64f(W + h * 65536 + dt * 4096, 64, Bt + h * 65536 + dt * 64, 1024, lds);
}

// ---------------------------------------------------------------------------
// Double-buffered 1-barrier GEMM: C = (A[M,K] @ Bt[N,K]^T + bias)*ascale.
// LDS chunk swizzle: slot (row, chunk) holds global chunk (chunk ^ (row&3));
// linear gload_lds dest + swizzled global source + swizzled read (rule #21).
// mbase/nbase are parameters (XCD panel-grouping remap done by caller).
// cmode: 0 bf16 row-major, 1 bf16 scatter Vt (fallback only), 2 f32 row-major,
//        3 bf16 coalesced-transpose into Vt[b,h,dk,t] (lA scratch >= 9216 B).
// ---------------------------------------------------------------------------
template <int F32>
__device__ __forceinline__ void stage16(const void* G, size_t eoff, ushort* ldst) {
  if (F32) {
    const float* p = (const float*)G + eoff;
    float4 x0 = *(const float4*)p;
    float4 x1 = *(const float4*)(p + 4);
    ushort t[8] __attribute__((aligned(16))) = {
        f2bf_rne(x0.x), f2bf_rne(x0.y), f2bf_rne(x0.z), f2bf_rne(x0.w),
        f2bf_rne(x1.x), f2bf_rne(x1.y), f2bf_rne(x1.z), f2bf_rne(x1.w)};
    *(uint4*)ldst = *(const uint4*)t;
  } else {
    gload16((const ushort*)G + eoff, ldst);
  }
}

template <int AF32, int BF32>
__device__ __forceinline__ void gemm_body_basic(const void* __restrict__ A,
                                                const void* __restrict__ Bt,
                                                const float* __restrict__ bias,
                                                void* __restrict__ C, int cmode,
                                                float ascale, int N, int K, int mbase,
                                                int nbase, ushort* lA, ushort* lB) {
  const int tid = threadIdx.x;
  const int l = tid & 63, lane15 = l & 15, quad = l >> 4;
  const int w = tid >> 6;
  const int wrow = (w >> 1) * 64, wcol = (w & 1) * 64;
  const int e0 = tid * 8;
  const int e1 = 2048 + tid * 8;
  const int r0 = tid >> 2;        // rows 0..63 (e0); e1 rows r0+64
  const int r1 = r0 + 64;
  const int cs = ((tid & 3) ^ (r0 & 3)) * 8;
  const int rsw = lane15 & 3;     // read-side row-swizzle bits

  float4v acc[4][4];
#pragma unroll
  for (int i = 0; i < 4; ++i)
#pragma unroll
    for (int j = 0; j < 4; ++j) acc[i][j] = (float4v){0.f, 0.f, 0.f, 0.f};

  // prologue: stage kb=0 into buffer 0
  stage16<AF32>(A, (size_t)(mbase + r0) * K + cs, &lA[e0]);
  stage16<AF32>(A, (size_t)(mbase + r1) * K + cs, &lA[e1]);
  stage16<BF32>(Bt, (size_t)(nbase + r0) * K + cs, &lB[e0]);
  stage16<BF32>(Bt, (size_t)(nbase + r1) * K + cs, &lB[e1]);
  asm volatile("s_waitcnt vmcnt(0)" ::: "memory");
  __syncthreads();

  int cur = 0;
  for (int kb = 0; kb < K; kb += 32) {
    const int nxt = cur ^ 1;
    if (kb + 32 < K) {
      stage16<AF32>(A, (size_t)(mbase + r0) * K + cs + kb + 32, &lA[nxt * 4096 + e0]);
      stage16<AF32>(A, (size_t)(mbase + r1) * K + cs + kb + 32, &lA[nxt * 4096 + e1]);
      stage16<BF32>(Bt, (size_t)(nbase + r0) * K + cs + kb + 32, &lB[nxt * 4096 + e0]);
      stage16<BF32>(Bt, (size_t)(nbase + r1) * K + cs + kb + 32, &lB[nxt * 4096 + e1]);
    }
    const ushort* cA = &lA[cur * 4096];
    const ushort* cB = &lB[cur * 4096];
    short8 a[4], b[4];
#pragma unroll
    for (int i = 0; i < 4; ++i) {
      a[i] = *(const short8*)&cA[(wrow + i * 16 + lane15) * 32 + (quad ^ rsw) * 8];
      b[i] = *(const short8*)&cB[(wcol + i * 16 + lane15) * 32 + (quad ^ rsw) * 8];
    }
#pragma unroll
    for (int i = 0; i < 4; ++i)
#pragma unroll
      for (int j = 0; j < 4; ++j) acc[i][j] = MFMA16(a[i], b[j], acc[i][j]);
    asm volatile("s_waitcnt vmcnt(0)" ::: "memory");
    __syncthreads();
    cur = nxt;
  }

  if (cmode == 3) {
    // coalesced transposed epilogue into Vt[b,h,dk,t] via per-wave LDS scratch
    __syncthreads();
    uint* sp = (uint*)lA + w * 576;  // 2304 B/wave, lA is 16 KB
    const int bb = mbase >> 11;
    const int tb = (mbase & 2047) + wrow;
#pragma unroll
    for (int j = 0; j < 4; ++j) {
      {
        const int n = nbase + wcol + j * 16 + lane15;
        const float bvs = bias[n];
#pragma unroll
        for (int i = 0; i < 4; ++i)
#pragma unroll
          for (int rp = 0; rp < 2; ++rp) {
            const uint lo = f2bf_rne((acc[i][j][2 * rp] + bvs) * ascale);
            const uint hi = f2bf_rne((acc[i][j][2 * rp + 1] + bvs) * ascale);
            sp[36 * lane15 + i * 8 + quad * 2 + rp] = lo | (hi << 16);
          }
      }
#pragma unroll
      for (int t = 0; t < 2; ++t) {
        const int row = t * 8 + (l >> 3);
        const int c = l & 7;
        uint4 d = *(const uint4*)(sp + 36 * row + 4 * c);
        const int ng = nbase + wcol + j * 16 + row;
        ushort* dst = (ushort*)C + ((size_t)(bb * 1024 + ng)) * 2048 + tb + c * 8;
        *(uint4*)dst = d;
      }
    }
    return;
  }

#pragma unroll
  for (int j = 0; j < 4; ++j) {
    const int n = nbase + wcol + j * 16 + lane15;
    const float bvs = bias[n];
#pragma unroll
    for (int i = 0; i < 4; ++i) {
      const int m0 = mbase + wrow + i * 16 + quad * 4;
#pragma unroll
      for (int r = 0; r < 4; ++r) {
        const float val = (acc[i][j][r] + bvs) * ascale;
        if (cmode == 1) {
          const int m = m0 + r;
          const int bb = m >> 11, t = m & 2047;
          ((ushort*)C)[((size_t)(bb * 1024 + n)) * 2048 + t] = f2bf_rne(val);
        } else if (cmode == 2) {
          ((float*)C)[(size_t)(m0 + r) * N + n] = val;
        } else {
          ((ushort*)C)[(size_t)(m0 + r) * N + n] = f2bf_rne(val);
        }
      }
    }
  }
}

// main-path projections (bf16 operands via gload_lds, coalesced Vt epilogue).
// 1-D grid 768 with XCD panel-grouping (768%8==0, bijective).
// R11: __launch_bounds__(256, 3) -> 3 blocks/CU; 256 CU x 3 = 768 = grid, so
// ALL blocks co-resident (tail eliminated) and 12 waves/CU hide latency
// (R8 counters: MfmaUtil 21 / VALUBusy 13.5 / Occ 25.6 = latency-bound).
// LDS 3x32KB = 96KB <= 160KB; VGPR 64 <= 512/3.
__global__ __launch_bounds__(256, 3) void proj3_kernel(
    const ushort* __restrict__ Qb, const ushort* __restrict__ Kb,
    const ushort* __restrict__ Vb, const ushort* __restrict__ BtQ,
    const ushort* __restrict__ BtK, const ushort* __restrict__ BtV,
    const float* __restrict__ bq, const float* __restrict__ bk,
    const float* __restrict__ bv, ushort* __restrict__ Qh, ushort* __restrict__ Kh,
    ushort* __restrict__ Vt) {
  __shared__ ushort lA[8192], lB[8192];
  const int lin = blockIdx.x;
  const int xcd = lin & 7;
  const int slot = lin >> 3;
  const int panel = xcd * 12 + (slot >> 3);  // 0..95
  const int nb = slot & 7;
  const int zz = panel >> 5;       // 0..2
  const int yb = panel & 31;       // 0..31
  const int mbase = yb * 128, nbase = nb * 128;
  if (zz == 0)
    gemm_body_basic<0, 0>(Qb, BtQ, bq, Qh, 0, CEXP, 1024, 1024, mbase, nbase, lA, lB);
  else if (zz == 1)
    gemm_body_basic<0, 0>(Kb, BtK, bk, Kh, 0, 1.0f, 1024, 1024, mbase, nbase, lA, lB);
  else
    gemm_body_basic<0, 0>(Vb, BtV, bv, Vt, 3, 1.0f, 1024, 1024, mbase, nbase, lA, lB);
}

// ---------------------------------------------------------------------------
// Output projection: 128(M)x64(N) tiles, 1-D grid 512 with XCD grouping
// (512 = 256 CU x 2 blocks/CU: already a perfect resident fit).
// Double-buffered (24 KB LDS), one barrier per K-step, chunk-swizzled LDS.
// ---------------------------------------------------------------------------
__global__ __launch_bounds__(256, 2) void gemm_out_kernel(
    const ushort* __restrict__ X, const ushort* __restrict__ WoB,
    const float* __restrict__ bo, float* __restrict__ out) {
  __shared__ ushort lA[8192], lB[4096];
  const int lin = blockIdx.x;
  const int xcd = lin & 7;
  const int slot = lin >> 3;        // 0..63
  const int panel = xcd * 4 + (slot >> 4);  // 0..31
  const int nb = slot & 15;
  const int mbase = panel * 128, nbase = nb * 64;
  const int tid = threadIdx.x;
  const int l = tid & 63, lane15 = l & 15, quad = l >> 4;
  const int wv = tid >> 6;
  const int wrow = wv * 32;
  const int e0 = tid * 8;
  const int e1 = 2048 + tid * 8;
  const int r0 = tid >> 2;
  const int r1 = r0 + 64;
  const int cs = ((tid & 3) ^ (r0 & 3)) * 8;
  const int rsw = lane15 & 3;
  const ushort* Ag0 = X + (size_t)(mbase + r0) * 1024 + cs;
  const ushort* Ag1 = X + (size_t)(mbase + r1) * 1024 + cs;
  const ushort* Bg0 = WoB + (size_t)(nbase + r0) * 1024 + cs;

  float4v acc[2][4];
#pragma unroll
  for (int i = 0; i < 2; ++i)
#pragma unroll
    for (int j = 0; j < 4; ++j) acc[i][j] = (float4v){0.f, 0.f, 0.f, 0.f};

  // prologue: stage kb=0 into buffer 0
  gload16(Ag0, &lA[e0]);
  gload16(Ag1, &lA[e1]);
  gload16(Bg0, &lB[e0]);
  asm volatile("s_waitcnt vmcnt(0)" ::: "memory");
  __syncthreads();

  int cur = 0;
  for (int kb = 0; kb < 1024; kb += 32) {
    const int nxt = cur ^ 1;
    if (kb + 32 < 1024) {
      gload16(Ag0 + kb + 32, &lA[nxt * 4096 + e0]);
      gload16(Ag1 + kb + 32, &lA[nxt * 4096 + e1]);
      gload16(Bg0 + kb + 32, &lB[nxt * 2048 + e0]);
    }
    const ushort* cA = &lA[cur * 4096];
    const ushort* cB = &lB[cur * 2048];
    short8 a[2], b[4];
#pragma unroll
    for (int i = 0; i < 2; ++i)
      a[i] = *(const short8*)&cA[(wrow + i * 16 + lane15) * 32 + (quad ^ rsw) * 8];
#pragma unroll
    for (int j = 0; j < 4; ++j)
      b[j] = *(const short8*)&cB[(j * 16 + lane15) * 32 + (quad ^ rsw) * 8];
#pragma unroll
    for (int i = 0; i < 2; ++i)
#pragma unroll
      for (int j = 0; j < 4; ++j) acc[i][j] = MFMA16(a[i], b[j], acc[i][j]);
    asm volatile("s_waitcnt vmcnt(0)" ::: "memory");
    __syncthreads();
    cur = nxt;
  }

#pragma unroll
  for (int j = 0; j < 4; ++j) {
    const int n = nbase + j * 16 + lane15;
    const float bvs = bo[n];
#pragma unroll
    for (int i = 0; i < 2; ++i) {
      const int m0 = mbase + wrow + i * 16 + quad * 4;
#pragma unroll
      for (int r = 0; r < 4; ++r) out[(size_t)(m0 + r) * 1024 + n] = acc[i][j][r] + bvs;
    }
  }
}

// fallback-path kernels (f32 operands)
__global__ __launch_bounds__(256, 2) void proj3f_kernel(
    const float* __restrict__ Q, const float* __restrict__ Kin,
    const float* __restrict__ V, const ushort* __restrict__ BtQ,
    const ushort* __restrict__ BtK, const ushort* __restrict__ BtV,
    const float* __restrict__ bq, const float* __restrict__ bk,
    const float* __restrict__ bv, ushort* __restrict__ Qh, ushort* __restrict__ Kh,
    ushort* __restrict__ Vt) {
  __shared__ ushort lA[8192], lB[8192];
  const int mbase = blockIdx.y * 128, nbase = blockIdx.x * 128;
  if (blockIdx.z == 0)
    gemm_body_basic<1, 0>(Q, BtQ, bq, Qh, 0, CEXP, 1024, 1024, mbase, nbase, lA, lB);
  else if (blockIdx.z == 1)
    gemm_body_basic<1, 0>(Kin, BtK, bk, Kh, 0, 1.0f, 1024, 1024, mbase, nbase, lA, lB);
  else
    gemm_body_basic<1, 0>(V, BtV, bv, Vt, 3, 1.0f, 1024, 1024, mbase, nbase, lA, lB);
}

__global__ __launch_bounds__(256, 2) void gemm_btf_kernel(
    const ushort* __restrict__ X, const float* __restrict__ Wo,
    const float* __restrict__ bo, float* __restrict__ out) {
  __shared__ ushort lA[8192], lB[8192];
  const int mbase = blockIdx.y * 128, nbase = blockIdx.x * 128;
  gemm_body_basic<0, 1>(X, Wo, bo, out, 2, 1.0f, 1024, 1024, mbase, nbase, lA, lB);
}

// ---------------------------------------------------------------------------
// Flash attention v11 (verified 43.7 us): pipe-interleaved tile body on v6's
// verified sync structure. QK-all -> sm-half1 -> V-reads -> PV-half1 ->
// sm-half2 -> PV-half2; one vmcnt(0)+barrier per tile. UNTOUCHED this round.
// ---------------------------------------------------------------------------
__global__ __launch_bounds__(512, 4) void attn_kernel(const ushort* __restrict__ Qh,
                                                      const ushort* __restrict__ Kh,
                                                      const ushort* __restrict__ Vt,
                                                      ushort* __restrict__ ctxout) {
  __shared__ ushort lK[2][64 * 64];
  __shared__ ushort lV[2][64 * 64];
  const int tid = threadIdx.x, l = tid & 63, wv = tid >> 6;
  const int lane15 = l & 15, quad = l >> 4;
  const int bh = blockIdx.x, b = bh >> 4, h = bh & 15;
  const int q0 = blockIdx.y * 128 + wv * 16;

  const int sr = tid >> 3;
  const int scb = (tid & 7) ^ (sr & 7);
  const ushort* Kp = Kh + (size_t)(b * 2048) * 1024 + h * 64;
  const ushort* Vp = Vt + (size_t)(bh * 64) * 2048;
  const ushort* Kg = Kp + (size_t)sr * 1024 + scb * 8;
  const ushort* Vg = Vp + (size_t)sr * 2048 + scb * 8;

  const ushort* qrow = Qh + (size_t)(b * 2048 + q0 + lane15) * 1024 + h * 64;
  const short8 qa0 = *(const short8*)&qrow[quad * 8];
  const short8 qa1 = *(const short8*)&qrow[32 + quad * 8];

  const int xm = lane15 & 7;
  const int fr0 = lane15 * 64 + ((quad ^ xm) * 8);
  const int fr1 = lane15 * 64 + (((quad + 4) ^ xm) * 8);

  const short8 ones = {0x3F80, 0x3F80, 0x3F80, 0x3F80, 0x3F80, 0x3F80, 0x3F80, 0x3F80};

  float4v o[4];
  float4v lf = (float4v){0.f, 0.f, 0.f, 0.f};
#pragma unroll
  for (int i = 0; i < 4; ++i) o[i] = (float4v){0.f, 0.f, 0.f, 0.f};

  gload16(Kg, &lK[0][tid * 8]);
  gload16(Vg, &lV[0][tid * 8]);
  asm volatile("s_waitcnt vmcnt(0)" ::: "memory");
  __syncthreads();

  union PK { uint w[4]; short8 v; };

  int cur = 0;
  for (int s0 = 0; s0 < 2048; s0 += 64) {
    if (s0 + 64 < 2048) {
      gload16(Kg + (size_t)(s0 + 64) * 1024, &lK[cur ^ 1][tid * 8]);
      gload16(Vg + (s0 + 64), &lV[cur ^ 1][tid * 8]);
    }
    const ushort* Kl = &lK[cur][0];
    const ushort* Vl = &lV[cur][0];

    // --- QK for all 4 s-16-blocks (8 MFMAs fill the matrix pipe) ---
    float4v sb[4];
    __builtin_amdgcn_s_setprio(1);
#pragma unroll
    for (int i = 0; i < 4; ++i) {
      short8 k0 = *(const short8*)&Kl[i * 1024 + fr0];
      short8 k1 = *(const short8*)&Kl[i * 1024 + fr1];
      float4v c = (float4v){0.f, 0.f, 0.f, 0.f};
      c = MFMA16(k0, qa0, c);
      c = MFMA16(k1, qa1, c);
      sb[i] = c;
    }
    __builtin_amdgcn_s_setprio(0);

    // --- softmax half 1 (i=0,1) -> pa0, under the QK pipe drain ---
    uint wpk[4][2];
#pragma unroll
    for (int i = 0; i < 2; ++i) {
      const float e0 = __builtin_amdgcn_exp2f(sb[i][0]);
      const float e1 = __builtin_amdgcn_exp2f(sb[i][1]);
      const float e2 = __builtin_amdgcn_exp2f(sb[i][2]);
      const float e3 = __builtin_amdgcn_exp2f(sb[i][3]);
      asm("v_cvt_pk_bf16_f32 %0, %1, %2" : "=v"(wpk[i][0]) : "v"(e0), "v"(e1));
      asm("v_cvt_pk_bf16_f32 %0, %1, %2" : "=v"(wpk[i][1]) : "v"(e2), "v"(e3));
    }
    PK u0;
    {
      uint a0 = wpk[0][0], b0 = wpk[1][0];
      asm("v_permlane32_swap_b32 %0, %1" : "+v"(a0), "+v"(b0));
      asm("v_permlane16_swap_b32 %0, %1" : "+v"(a0), "+v"(b0));
      uint a1 = wpk[0][1], b1 = wpk[1][1];
      asm("v_permlane32_swap_b32 %0, %1" : "+v"(a1), "+v"(b1));
      asm("v_permlane16_swap_b32 %0, %1" : "+v"(a1), "+v"(b1));
      u0.w[0] = a0; u0.w[1] = a1; u0.w[2] = b0; u0.w[3] = b1;
    }
    const short8 pa0 = u0.v;

    // --- V fragment reads (ds pipe runs under MFMA issue) ---
    short8 vv0[4], vv1[4];
#pragma unroll
    for (int nf = 0; nf < 4; ++nf) {
      vv0[nf] = *(const short8*)&Vl[nf * 1024 + fr0];
      vv1[nf] = *(const short8*)&Vl[nf * 1024 + fr1];
    }

    // --- PV half 1 (pa0) fills the matrix pipe... ---
    __builtin_amdgcn_s_setprio(1);
    lf = MFMA16(pa0, ones, lf);
#pragma unroll
    for (int nf = 0; nf < 4; ++nf) o[nf] = MFMA16(pa0, vv0[nf], o[nf]);
    __builtin_amdgcn_s_setprio(0);

    // --- ...while softmax half 2 (i=2,3) -> pa1 runs on VALU/trans ---
#pragma unroll
    for (int i = 2; i < 4; ++i) {
      const float e0 = __builtin_amdgcn_exp2f(sb[i][0]);
      const float e1 = __builtin_amdgcn_exp2f(sb[i][1]);
      const float e2 = __builtin_amdgcn_exp2f(sb[i][2]);
      const float e3 = __builtin_amdgcn_exp2f(sb[i][3]);
      asm("v_cvt_pk_bf16_f32 %0, %1, %2" : "=v"(wpk[i][0]) : "v"(e0), "v"(e1));
      asm("v_cvt_pk_bf16_f32 %0, %1, %2" : "=v"(wpk[i][1]) : "v"(e2), "v"(e3));
    }
    PK u1;
    {
      uint a2 = wpk[2][0], b2 = wpk[3][0];
      asm("v_permlane32_swap_b32 %0, %1" : "+v"(a2), "+v"(b2));
      asm("v_permlane16_swap_b32 %0, %1" : "+v"(a2), "+v"(b2));
      uint a3 = wpk[2][1], b3 = wpk[3][1];
      asm("v_permlane32_swap_b32 %0, %1" : "+v"(a3), "+v"(b3));
      asm("v_permlane16_swap_b32 %0, %1" : "+v"(a3), "+v"(b3));
      u1.w[0] = a2; u1.w[1] = a3; u1.w[2] = b2; u1.w[3] = b3;
    }
    const short8 pa1 = u1.v;

    // --- PV half 2 (pa1) ---
    __builtin_amdgcn_s_setprio(1);
    lf = MFMA16(pa1, ones, lf);
#pragma unroll
    for (int nf = 0; nf < 4; ++nf) o[nf] = MFMA16(pa1, vv1[nf], o[nf]);
    __builtin_amdgcn_s_setprio(0);

    asm volatile("s_waitcnt vmcnt(0)" ::: "memory");
    __syncthreads();
    cur ^= 1;
  }

  float inv[4];
#pragma unroll
  for (int r = 0; r < 4; ++r) inv[r] = (lf[r] > 0.f) ? 1.0f / lf[r] : 0.0f;
  ushort* crow = ctxout + ((size_t)bh * 2048 + q0) * 64;
#pragma unroll
  for (int nf = 0; nf < 4; ++nf)
#pragma unroll
    for (int r = 0; r < 4; ++r)
      crow[(size_t)(quad * 4 + r) * 64 + nf * 16 + lane15] = f2bf_rne(o[nf][r] * inv[r]);
}

// ---------------------------------------------------------------------------
extern "C" void kernel_launch(void* const* d_in, const int* in_sizes, int n_in,
                              void* d_out, int out_size, void* d_ws, size_t ws_size,
                              hipStream_t stream) {
  const float* Q = (const float*)d_in[0];
  const float* K = (const float*)d_in[1];
  const float* V = (const float*)d_in[2];
  const float* Wq = (const float*)d_in[3];
  const float* bq = (const float*)d_in[4];
  const float* Wk = (const float*)d_in[5];
  const float* bk = (const float*)d_in[6];
  const float* Wv = (const float*)d_in[7];
  const float* bv = (const float*)d_in[8];
  const float* Wo = (const float*)d_in[9];
  const float* bo = (const float*)d_in[10];
  float* out = (float*)d_out;
  ushort* ws = (ushort*)d_ws;

  if (ws_size >= (58ull << 20)) {
    // big path (58 MB, u16 units):
    // [Qh 4M][Kh 4M][Vt 4M][Bt 3M (X 4M aliases)][WoB 1M @16M][Qb 4M][Kb 4M][Vb 4M]
    ushort* Qh = ws;
    ushort* Kh = Qh + (4 << 20);
    ushort* Vt = Kh + (4 << 20);
    ushort* BtQ = Vt + (4 << 20);
    ushort* BtK = BtQ + (1 << 20);
    ushort* BtV = BtK + (1 << 20);
    ushort* X = BtQ;  // 4M; Bt dead after proj3
    ushort* WoB = ws + (16ull << 20);
    ushort* Qb = WoB + (1 << 20);
    ushort* Kb = Qb + (4 << 20);
    ushort* Vb = Kb + (4 << 20);

    prep_kernel<<<dim3(7424), 256, 0, stream>>>(Q, K, V, Wo, Wq, Wk, Wv, Qb, Kb, Vb,
                                                WoB, BtQ, BtK, BtV);
    proj3_kernel<<<dim3(768), 256, 0, stream>>>(Qb, Kb, Vb, BtQ, BtK, BtV, bq, bk, bv,
                                                Qh, Kh, Vt);
    attn_kernel<<<dim3(32, 16), 512, 0, stream>>>(Qh, Kh, Vt, X);
    gemm_out_kernel<<<dim3(512), 256, 0, stream>>>(X, WoB, bo, out);
  } else {
    // fallback (32 MB): f32 A/B staging in the GEMMs
    ushort* Qh = ws;
    ushort* Kh = Qh + (4 << 20);
    ushort* Vt = Kh + (4 << 20);
    ushort* R = Vt + (4 << 20);
    ushort* BtQ = R;
    ushort* BtK = R + (1 << 20);
    ushort* BtV = R + (2 << 20);
    ushort* X = R;

    repack_w_kernel<<<dim3(16, 16, 3), 256, 0, stream>>>(Wq, Wk, Wv, BtQ, BtK, BtV);
    proj3f_kernel<<<dim3(8, 32, 3), 256, 0, stream>>>(Q, K, V, BtQ, BtK, BtV, bq, bk, bv,
                                                      Qh, Kh, Vt);
    attn_kernel<<<dim3(32, 16), 512, 0, stream>>>(Qh, Kh, Vt, X);
    gemm_btf_kernel<<<dim3(8, 32), 256, 0, stream>>>(X, Wo, bo, out);
  }
}